// Round 14
// baseline (52.479 us; speedup 1.0000x reference)
//
#include <hip/hip_runtime.h>

#define KN      1024
#define FAN_IN  16
#define NSP     64
#define MAPB    (NSP * NSP)
#define THRESH  12

__device__ __forceinline__ float tanh_fast(float x) {
    float ax = fabsf(x);
    float e  = __expf(-2.0f * ax);
    float r  = 1.0f - 2.0f * e * __builtin_amdgcn_rcpf(1.0f + e);
    return copysignf(r, x);
}

// Full-wave DPP shifts; bound_ctrl=1 zeroes shifted-in edge lane = conv zero-pad
// at col 0 / col 63. Proven in R9/R10.
__device__ __forceinline__ float dpp_wshr1(float x) {  // lane L <- lane L-1
    return __int_as_float(__builtin_amdgcn_update_dpp(
        0, __float_as_int(x), 0x138, 0xF, 0xF, true));
}
__device__ __forceinline__ float dpp_wshl1(float x) {  // lane L <- lane L+1
    return __int_as_float(__builtin_amdgcn_update_dpp(
        0, __float_as_int(x), 0x130, 0xF, 0xF, true));
}

// 1 block = 1 node, 512 threads = 8 waves = {channel-group g 0..3} x {row-half h 0..1}.
// Wave: 4 channels x 32 output rows (lane = column), 32 register accumulators,
// 34 coalesced row-loads per channel. sched_barrier(0) pins the full load batch
// BEFORE the FMA stream -> 34 outstanding loads, drained progressively by
// use-order vmcnt. No barriers in the main loop; one __syncthreads(), 4-way
// LDS reduce + bias + tanh + store.
// R13 vs R12: __launch_bounds__(512) (no wave min -> no 64-VGPR strangulation),
// + sched_barrier between load batch and compute.
__global__ __launch_bounds__(512) void decoder_kernel(
    const float* __restrict__ prev_outputs,      // [1024,64,64]
    const void*  __restrict__ prev_is_active,    // [1024] bool(1B) or int32 (sniffed)
    const int*   __restrict__ parent_indices,    // [1024,16]
    const float* __restrict__ Wt,                // [1024,16,3,3]
    const float* __restrict__ bias,              // [1024]
    float*       __restrict__ out)               // [1024*4096] + [1024] activity
{
    __shared__ float slab[8][32][NSP];           // 8 x 8 KB = 64 KB partials

    const int k    = blockIdx.x;
    const int tid  = threadIdx.x;
    const int lane = tid & 63;                   // column
    const int wv   = tid >> 6;                   // wave id
    const int g    = wv >> 1;                    // channel group 0..3
    const int h    = wv & 1;                     // row half 0..1

    // --- sniff flag encoding: numpy bool (1 byte) vs int32. Deterministic. ---
    bool bytemode = false;
    {
        const unsigned* sv = (const unsigned*)prev_is_active;
        #pragma unroll
        for (int i = 0; i < 16; ++i)
            if (sv[i] > 1u) bytemode = true;
    }

    // --- activity gate (uniform scalar work) ---
    const int* pidx = parent_indices + k * FAN_IN;
    int cnt = 0;
    #pragma unroll
    for (int i = 0; i < FAN_IN; ++i) {
        int p = pidx[i];
        int f;
        if (bytemode) f = (((const unsigned char*)prev_is_active)[p] != 0);
        else          f = (((const int*)prev_is_active)[p] != 0);
        cnt += f;
    }
    const bool active = (cnt >= THRESH);

    const size_t obase = (size_t)k * MAPB;
    if (tid == 0)
        out[(size_t)KN * MAPB + k] = active ? 1.0f : 0.0f;

    if (!active) {                   // uniform early-exit: barrier never reached
        float4 z = make_float4(0.f, 0.f, 0.f, 0.f);
        float4* o4 = (float4*)(out + obase);
        o4[tid]       = z;
        o4[tid + 512] = z;
        return;
    }

    // wave-uniform row-boundary machinery.
    // Input global rows for this half: gbase+j, j=0..33, gbase = h*32 - 1.
    // j=0 OOB for h=0 (row -1); j=33 OOB for h=1 (row 64). Value-masked.
    const int   gbase = h * 32 - 1;
    const float mT = (h == 1) ? 1.0f : 0.0f;
    const float mB = (h == 0) ? 1.0f : 0.0f;
    const int   gT = (h == 1) ? 31 : 0;          // clamped row for j=0
    const int   gB = (h == 0) ? 32 : 63;         // clamped row for j=33

    const float* wbase = Wt + (size_t)k * FAN_IN * 9;

    float acc[32];
    #pragma unroll
    for (int a = 0; a < 32; ++a) acc[a] = 0.0f;

    #pragma unroll 1
    for (int cc = 0; cc < 4; ++cc) {
        const int ch = g * 4 + cc;
        const int p  = pidx[ch];                              // uniform -> s_load
        const float* __restrict__ src = prev_outputs + (size_t)p * MAPB + lane;

        // ---- 34 independent coalesced loads, issued as one batch ----
        float row[34];
        row[0] = src[gT * NSP];
        #pragma unroll
        for (int j = 1; j <= 32; ++j) row[j] = src[(gbase + j) * NSP];
        row[33] = src[gB * NSP];

        // pin: every load above issues before any compute below
        __builtin_amdgcn_sched_barrier(0);

        row[0]  *= mT;
        row[33] *= mB;

        const float* w = wbase + ch * 9;                      // uniform -> s_loads
        const float wl[3] = { w[0], w[3], w[6] };
        const float wc[3] = { w[1], w[4], w[7] };
        const float wr[3] = { w[2], w[5], w[8] };

        // input row gbase+j feeds local out rows a = j-t (t = weight row 0..2)
        #pragma unroll
        for (int j = 0; j < 34; ++j) {
            const float l = dpp_wshr1(row[j]);
            const float r = dpp_wshl1(row[j]);
            #pragma unroll
            for (int t = 0; t < 3; ++t) {
                const int a = j - t;
                if (a >= 0 && a < 32)
                    acc[a] = fmaf(wl[t], l,
                              fmaf(wc[t], row[j],
                               fmaf(wr[t], r, acc[a])));
            }
        }
    }

    // publish partials, single barrier, 4-way reduce + epilogue
    #pragma unroll
    for (int a = 0; a < 32; ++a) slab[wv][a][lane] = acc[a];

    __syncthreads();

    const float bk = bias[k];
    #pragma unroll
    for (int n = 0; n < 8; ++n) {                // 8 x 512 = 4096 = MAPB exactly
        const int i   = tid + n * 512;           // 0..4095
        const int r_  = i >> 6;                  // global out row 0..63
        const int col = i & 63;
        const int h2  = r_ >> 5;                 // 0..1
        const int a   = r_ & 31;
        const float s = slab[h2][a][col] + slab[2 + h2][a][col]
                      + slab[4 + h2][a][col] + slab[6 + h2][a][col];
        out[obase + (size_t)r_ * NSP + col] = tanh_fast(s + bk);
    }
}

extern "C" void kernel_launch(void* const* d_in, const int* in_sizes, int n_in,
                              void* d_out, int out_size, void* d_ws, size_t ws_size,
                              hipStream_t stream) {
    const float* prev_outputs   = (const float*)d_in[0];
    const void*  prev_is_active = d_in[1];
    const int*   parent_indices = (const int*)d_in[2];
    const float* Wt             = (const float*)d_in[3];
    const float* bias           = (const float*)d_in[4];
    float*       out            = (float*)d_out;

    decoder_kernel<<<dim3(KN), dim3(512), 0, stream>>>(
        prev_outputs, prev_is_active, parent_indices, Wt, bias, out);
}

// Round 15
// 41.876 us; speedup vs baseline: 1.2532x; 1.2532x over previous
//
#include <hip/hip_runtime.h>

#define KN      1024
#define FAN_IN  16
#define NSP     64
#define MAPB    (NSP * NSP)
#define THRESH  12

__device__ __forceinline__ float tanh_fast(float x) {
    float ax = fabsf(x);
    float e  = __expf(-2.0f * ax);
    float r  = 1.0f - 2.0f * e * __builtin_amdgcn_rcpf(1.0f + e);
    return copysignf(r, x);
}

// Full-wave DPP shifts; bound_ctrl=1 zeroes shifted-in edge lane = conv zero-pad
// at col 0 / col 63. Proven in R9/R10.
__device__ __forceinline__ float dpp_wshr1(float x) {  // lane L <- lane L-1
    return __int_as_float(__builtin_amdgcn_update_dpp(
        0, __float_as_int(x), 0x138, 0xF, 0xF, true));
}
__device__ __forceinline__ float dpp_wshl1(float x) {  // lane L <- lane L+1
    return __int_as_float(__builtin_amdgcn_update_dpp(
        0, __float_as_int(x), 0x130, 0xF, 0xF, true));
}

__device__ __forceinline__ void gload_lds16f(const float* g, float* l) {
    __builtin_amdgcn_global_load_lds(
        (const __attribute__((address_space(1))) unsigned*)g,
        (__attribute__((address_space(3)))       unsigned*)l,
        16, 0, 0);
}

// R9 base (best: 39.1 us) + T4: counted vmcnt + raw s_barrier, 3-buffer
// depth-2 prefetch. 1 block = 1 node, 512 threads (8 waves); wave wv owns
// output rows 8wv..8wv+7, lane = column. Per channel: whole 16 KB map in LDS;
// compute = 10 row reads + DPP halos + 72 FMA. The per-channel __syncthreads
// of R9 (which drained vmcnt to 0, serializing every DMA) is replaced by
// s_waitcnt vmcnt(2) + s_barrier: the next channel's stage stays in flight
// across the barrier.
__global__ __launch_bounds__(512) void decoder_kernel(
    const float* __restrict__ prev_outputs,      // [1024,64,64]
    const void*  __restrict__ prev_is_active,    // [1024] bool(1B) or int32 (sniffed)
    const int*   __restrict__ parent_indices,    // [1024,16]
    const float* __restrict__ Wt,                // [1024,16,3,3]
    const float* __restrict__ bias,              // [1024]
    float*       __restrict__ out)               // [1024*4096] + [1024] activity
{
    __shared__ float sbuf[3][MAPB];              // 3 x 16 KB = 48 KB

    const int k    = blockIdx.x;
    const int tid  = threadIdx.x;
    const int lane = tid & 63;                   // column
    const int wv   = tid >> 6;                   // wave id, uniform
    const int r0   = wv * 8;                     // first of 8 output rows

    // --- sniff flag encoding: numpy bool (1 byte) vs int32. Deterministic. ---
    bool bytemode = false;
    {
        const unsigned* sv = (const unsigned*)prev_is_active;
        #pragma unroll
        for (int i = 0; i < 16; ++i)
            if (sv[i] > 1u) bytemode = true;
    }

    // --- activity gate (uniform scalar work) ---
    const int* pidx = parent_indices + k * FAN_IN;
    int cnt = 0;
    #pragma unroll
    for (int i = 0; i < FAN_IN; ++i) {
        int p = pidx[i];
        int f;
        if (bytemode) f = (((const unsigned char*)prev_is_active)[p] != 0);
        else          f = (((const int*)prev_is_active)[p] != 0);
        cnt += f;
    }
    const bool active = (cnt >= THRESH);

    const size_t obase = (size_t)k * MAPB;
    if (tid == 0)
        out[(size_t)KN * MAPB + k] = active ? 1.0f : 0.0f;

    if (!active) {                   // uniform early-exit: no barriers executed
        float4 z = make_float4(0.f, 0.f, 0.f, 0.f);
        float4* o4 = (float4*)(out + obase);
        o4[tid]       = z;
        o4[tid + 512] = z;
        return;
    }

    // uniform row-boundary machinery (cols handled by DPP bound_ctrl)
    const float mT = (wv > 0) ? 1.0f : 0.0f;
    const float mB = (wv < 7) ? 1.0f : 0.0f;
    const int   rT = (wv > 0) ? r0 - 1 : 0;
    const int   rB = (wv < 7) ? r0 + 8 : 63;

    const float* wbase = Wt + (size_t)k * FAN_IN * 9;

    float acc[8];
    #pragma unroll
    for (int s = 0; s < 8; ++s) acc[s] = 0.0f;

    // stage one 16 KB map into sbuf[b]: 512 lanes x 2 x 16 B (2 vmcnt events).
    // LDS base wave-uniform; global src per-lane (m104/m108 semantics).
#define STAGE(b, ch)                                                          \
    {                                                                         \
        const float* g = prev_outputs + (size_t)pidx[ch] * MAPB;              \
        gload_lds16f(g + tid * 4,        &sbuf[b][wv * 256]);                 \
        gload_lds16f(g + 2048 + tid * 4, &sbuf[b][2048 + wv * 256]);          \
    }

    // compute channel ch from buffer sb (R9 core, proven)
#define COMPUTE(sb_, ch)                                                      \
    {                                                                         \
        const float* sb = (sb_);                                              \
        const float* w  = wbase + (ch) * 9;                                   \
        const float wl0 = w[0], wc0 = w[1], wr0 = w[2];                       \
        const float wl1 = w[3], wc1 = w[4], wr1 = w[5];                       \
        const float wl2 = w[6], wc2 = w[7], wr2 = w[8];                       \
        float v[10], l[10], r[10];                                            \
        v[0] = sb[rT * NSP + lane] * mT;                                      \
        _Pragma("unroll")                                                     \
        for (int j = 1; j <= 8; ++j) v[j] = sb[(r0 - 1 + j) * NSP + lane];    \
        v[9] = sb[rB * NSP + lane] * mB;                                      \
        _Pragma("unroll")                                                     \
        for (int j = 0; j < 10; ++j) { l[j] = dpp_wshr1(v[j]); r[j] = dpp_wshl1(v[j]); } \
        _Pragma("unroll")                                                     \
        for (int s = 0; s < 8; ++s) {                                         \
            float a = acc[s];                                                 \
            a = fmaf(wl0, l[s],     fmaf(wc0, v[s],     fmaf(wr0, r[s],     a))); \
            a = fmaf(wl1, l[s + 1], fmaf(wc1, v[s + 1], fmaf(wr1, r[s + 1], a))); \
            a = fmaf(wl2, l[s + 2], fmaf(wc2, v[s + 2], fmaf(wr2, r[s + 2], a))); \
            acc[s] = a;                                                       \
        }                                                                     \
    }

    // prologue: two stages in flight
    STAGE(0, 0);
    STAGE(1, 1);

    #pragma unroll 1
    for (int ch = 0; ch < FAN_IN - 1; ++ch) {
        // complete stage ch (oldest); stage ch+1 remains in flight
        asm volatile("s_waitcnt vmcnt(2)" ::: "memory");
        __builtin_amdgcn_s_barrier();            // buf[ch%3] valid for all waves
        __builtin_amdgcn_sched_barrier(0);

        COMPUTE(sbuf[ch % 3], ch);

        // prefetch ch+2 into the buffer last read at iter ch-1 (safe: all waves
        // passed barrier ch, which is after their compute of ch-1)
        if (ch + 2 < FAN_IN) STAGE((ch + 2) % 3, ch + 2);
    }

    // final channel: drain everything
    asm volatile("s_waitcnt vmcnt(0)" ::: "memory");
    __builtin_amdgcn_s_barrier();
    __builtin_amdgcn_sched_barrier(0);
    COMPUTE(sbuf[(FAN_IN - 1) % 3], FAN_IN - 1);

#undef STAGE
#undef COMPUTE

    const float bk = bias[k];
    #pragma unroll
    for (int s = 0; s < 8; ++s)
        out[obase + (size_t)(r0 + s) * NSP + lane] = tanh_fast(acc[s] + bk);
}

extern "C" void kernel_launch(void* const* d_in, const int* in_sizes, int n_in,
                              void* d_out, int out_size, void* d_ws, size_t ws_size,
                              hipStream_t stream) {
    const float* prev_outputs   = (const float*)d_in[0];
    const void*  prev_is_active = d_in[1];
    const int*   parent_indices = (const int*)d_in[2];
    const float* Wt             = (const float*)d_in[3];
    const float* bias           = (const float*)d_in[4];
    float*       out            = (float*)d_out;

    decoder_kernel<<<dim3(KN), dim3(512), 0, stream>>>(
        prev_outputs, prev_is_active, parent_indices, Wt, bias, out);
}